// Round 3
// baseline (206.024 us; speedup 1.0000x reference)
//
#include <hip/hip_runtime.h>
#include <hip/hip_bf16.h>
#include <stdint.h>
#include <stddef.h>

#define D_MODEL 4096
#define RANK    64
#define GROUPQ  32

typedef __attribute__((ext_vector_type(4)))  float f32x4;
typedef __attribute__((ext_vector_type(16))) float f32x16;
typedef __attribute__((ext_vector_type(8)))  short bf16x8;

// packed f32 pair -> 2x bf16 (RNE) in one u32; compiler emits v_cvt_pk_bf16_f32
__device__ inline uint32_t pkbf(float a, float b) {
    union { __hip_bfloat162 t; uint32_t u; } c;
    c.t = __float22bfloat162_rn(make_float2(a, b));
    return c.u;
}

__device__ inline short f2bf1(float f) {
    union { __hip_bfloat16 t; short s; } c;
    c.t = __float2bfloat16(f);
    return c.s;
}

// ---------------------------------------------------------------------------
// Kernel 1: dequantize both weight matrices to bf16 in workspace.
//   a_deq[r][d] = qa_vals[r][d] * qa_scales[r][d/32]      (RANK x D_MODEL)
//   b_deq[d][r] = qb_vals[d][r] * qb_scales[d][r/32]      (D_MODEL x RANK)
// ---------------------------------------------------------------------------
__global__ void dequant_kernel(const int* __restrict__ qa, const float* __restrict__ qas,
                               const int* __restrict__ qb, const float* __restrict__ qbs,
                               short* __restrict__ a_deq, short* __restrict__ b_deq) {
    int idx = blockIdx.x * 256 + threadIdx.x;
    if (idx >= RANK * D_MODEL) return;
    {   // a: idx = r*D + d
        int r = idx / D_MODEL, d = idx - r * D_MODEL;
        a_deq[idx] = f2bf1((float)qa[idx] * qas[r * (D_MODEL / GROUPQ) + (d >> 5)]);
    }
    {   // b: idx = d*R + r
        int d = idx / RANK, r = idx - d * RANK;
        b_deq[idx] = f2bf1((float)qb[idx] * qbs[d * (RANK / GROUPQ) + (r >> 5)]);
    }
}

// ---------------------------------------------------------------------------
// Kernel 2: h[T][RANK] = x[T][D] @ a_deq[RANK][D]^T   (bf16 out, fp32 accum)
// Block: 512 threads = 8 waves; block owns 16 output rows; wave w owns
// K-range [w*512, (w+1)*512). mfma 16x16x32 bf16, 4 N-tiles (RANK=64).
// Cross-wave reduction through padded LDS (stride 68 -> no bank conflicts).
// x loads are direct global f32x4 pairs (16 rows x 128 B contiguous per
// instruction pair -> full-line coalescing); conversion via v_cvt_pk.
// ---------------------------------------------------------------------------
__global__ __launch_bounds__(512) void stage1_kernel(const float* __restrict__ x,
                                                     const short* __restrict__ a_deq,
                                                     short* __restrict__ h) {
    const int lane = threadIdx.x & 63;
    const int wave = threadIdx.x >> 6;
    const int base = blockIdx.x * 16;
    const int KW = D_MODEL / 8;                      // 512 per wave
    const int k_begin = wave * KW + ((lane >> 4) << 3);

    const float* xp  = x + (size_t)(base + (lane & 15)) * D_MODEL + k_begin;
    const short* ap0 = a_deq + (size_t)(lane & 15) * D_MODEL + k_begin;

    f32x4 acc[4] = {{0.f,0.f,0.f,0.f},{0.f,0.f,0.f,0.f},
                    {0.f,0.f,0.f,0.f},{0.f,0.f,0.f,0.f}};

    #pragma unroll 4
    for (int kk = 0; kk < KW; kk += 32) {
        f32x4 xv0 = *(const f32x4*)(xp + kk);
        f32x4 xv1 = *(const f32x4*)(xp + kk + 4);
        bf16x8 af;
        uint32_t* afu = (uint32_t*)&af;
        afu[0] = pkbf(xv0[0], xv0[1]);
        afu[1] = pkbf(xv0[2], xv0[3]);
        afu[2] = pkbf(xv1[0], xv1[1]);
        afu[3] = pkbf(xv1[2], xv1[3]);
        #pragma unroll
        for (int n = 0; n < 4; n++) {
            bf16x8 bf = *(const bf16x8*)(ap0 + (size_t)n * 16 * D_MODEL + kk);
            acc[n] = __builtin_amdgcn_mfma_f32_16x16x32_bf16(af, bf, acc[n], 0, 0, 0);
        }
    }

    // reduce the 8 waves' partial 16x64 tiles (stride 68 kills bank conflicts)
    __shared__ float red[8][16][68];   // 34816 B -> 4 blocks/CU
    #pragma unroll
    for (int n = 0; n < 4; n++)
        #pragma unroll
        for (int j = 0; j < 4; j++)
            red[wave][(lane >> 4) * 4 + j][n * 16 + (lane & 15)] = acc[n][j];
    __syncthreads();

    for (int e = threadIdx.x; e < 16 * 64; e += 512) {
        int r0 = e >> 6, c0 = e & 63;
        float s = 0.f;
        #pragma unroll
        for (int w = 0; w < 8; w++) s += red[w][r0][c0];
        h[(size_t)(base + r0) * RANK + c0] = f2bf1(s);
    }
}

// ---------------------------------------------------------------------------
// Kernel 3: out[T][D] = h[T][RANK] @ b_deq[D][RANK]^T   (fp32 out)
// mfma 32x32x16 bf16. Wave: 32 rows x 128 cols (4 tiles). Block: 4 waves
// side-by-side in N -> 32 rows x 512 cols. Grid (T/32, D/512).
// C layout: col = lane&31, row = (reg&3) + 8*(reg>>2) + 4*(lane>>5)
//  -> each store instruction writes 2 x 128B contiguous segments.
// ---------------------------------------------------------------------------
__global__ __launch_bounds__(256) void stage2_kernel(const short* __restrict__ h,
                                                     const short* __restrict__ b_deq,
                                                     float* __restrict__ out) {
    const int lane = threadIdx.x & 63;
    const int wave = threadIdx.x >> 6;
    const int rb = blockIdx.x * 32;
    const int cb = blockIdx.y * 512 + wave * 128;
    const int koff = (lane >> 5) << 3;

    const short* hp = h + (size_t)(rb + (lane & 31)) * RANK + koff;
    const short* bp = b_deq + (size_t)(cb + (lane & 31)) * RANK + koff;

    f32x16 acc[4];
    #pragma unroll
    for (int t = 0; t < 4; t++)
        #pragma unroll
        for (int j = 0; j < 16; j++) acc[t][j] = 0.f;

    #pragma unroll
    for (int k0 = 0; k0 < RANK; k0 += 16) {
        bf16x8 af = *(const bf16x8*)(hp + k0);
        #pragma unroll
        for (int t = 0; t < 4; t++) {
            bf16x8 bf = *(const bf16x8*)(bp + (size_t)t * 32 * RANK + k0);
            acc[t] = __builtin_amdgcn_mfma_f32_32x32x16_bf16(af, bf, acc[t], 0, 0, 0);
        }
    }

    #pragma unroll
    for (int t = 0; t < 4; t++) {
        #pragma unroll
        for (int reg = 0; reg < 16; reg++) {
            int r = (reg & 3) + 8 * (reg >> 2) + ((lane >> 5) << 2);
            int c = cb + t * 32 + (lane & 31);
            out[(size_t)(rb + r) * D_MODEL + c] = acc[t][reg];
        }
    }
}

// ---------------------------------------------------------------------------
extern "C" void kernel_launch(void* const* d_in, const int* in_sizes, int n_in,
                              void* d_out, int out_size, void* d_ws, size_t ws_size,
                              hipStream_t stream) {
    (void)n_in; (void)out_size; (void)ws_size;
    const float* x   = (const float*)d_in[0];
    const int*   qa  = (const int*)d_in[1];
    const float* qas = (const float*)d_in[2];
    const int*   qb  = (const int*)d_in[3];
    const float* qbs = (const float*)d_in[4];
    float* out = (float*)d_out;

    const int T = in_sizes[0] / D_MODEL;   // 16384

    // workspace layout (shorts): a_deq [64*4096], b_deq [4096*64], h [T*64]
    short* a_deq = (short*)d_ws;
    short* b_deq = a_deq + (size_t)RANK * D_MODEL;
    short* h     = b_deq + (size_t)D_MODEL * RANK;

    dequant_kernel<<<(RANK * D_MODEL + 255) / 256, 256, 0, stream>>>(qa, qas, qb, qbs,
                                                                     a_deq, b_deq);
    stage1_kernel<<<T / 16, 512, 0, stream>>>(x, a_deq, h);
    dim3 g2(T / 32, D_MODEL / 512);
    stage2_kernel<<<g2, 256, 0, stream>>>(h, b_deq, out);
}

// Round 4
// 144.436 us; speedup vs baseline: 1.4264x; 1.4264x over previous
//
#include <hip/hip_runtime.h>
#include <hip/hip_bf16.h>
#include <stdint.h>
#include <stddef.h>

#define D_MODEL 4096
#define RANK    64
#define KC      512                 // fp32 k-elements per chunk
#define NCH     (D_MODEL / KC)      // 8
#define M_BLK   32

typedef __attribute__((ext_vector_type(4)))  float f32x4;
typedef __attribute__((ext_vector_type(16))) float f32x16;
typedef __attribute__((ext_vector_type(8)))  short bf16x8;

__device__ inline short f2bf1(float f) {
    union { __hip_bfloat16 t; short s; } c;
    c.t = __float2bfloat16(f);
    return c.s;
}
__device__ inline uint32_t pkbf(float a, float b) {
    union { __hip_bfloat162 t; uint32_t u; } c;
    c.t = __float22bfloat162_rn(make_float2(a, b));
    return c.u;
}

// ---------------------------------------------------------------------------
// Dequant + pack both weights into MFMA-fragment order.
// apk: for k-block kb (32 wide), n-tile n (16 ranks), lane l:
//      apk[((kb*4+n)*64+l)*8 + j] = a[16n+(l&15)][kb*32+(l>>4)*8+j]
// bpk: for col-block cb (32 cols), k-step ks (16 wide), lane l:
//      bpk[((cb*4+ks)*64+l)*8 + j] = b[cb*32+(l&31)][ks*16+(l>>5)*8+j]
// -> every fragment load in the fused kernel is 64 lanes x 16 B contiguous.
// ---------------------------------------------------------------------------
__global__ __launch_bounds__(256) void dequant_pack_kernel(
        const int* __restrict__ qa, const float* __restrict__ qas,
        const int* __restrict__ qb, const float* __restrict__ qbs,
        short* __restrict__ apk, short* __restrict__ bpk) {
    const int idx = blockIdx.x * 256 + threadIdx.x;   // 0..32767
    const int l = idx & 63, t = idx >> 6;
    {   // a-side: t -> (kb, n)
        const int n = t & 3, kb = t >> 2;
        const int r = 16 * n + (l & 15);
        const int kbase = kb * 32 + ((l >> 4) << 3);
        const int* q = qa + (size_t)r * D_MODEL + kbase;
        const float s = qas[r * (D_MODEL / 32) + kb];
        bf16x8 o;
        #pragma unroll
        for (int j = 0; j < 8; ++j) o[j] = f2bf1((float)q[j] * s);
        *(bf16x8*)(apk + (size_t)idx * 8) = o;
    }
    {   // b-side: t -> (cb, ks)
        const int ks = t & 3, cb = t >> 2;
        const int d = cb * 32 + (l & 31);
        const int rbase = ks * 16 + ((l >> 5) << 3);
        const int* q = qb + (size_t)d * RANK + rbase;
        const float s = qbs[d * 2 + (ks >> 1)];
        bf16x8 o;
        #pragma unroll
        for (int j = 0; j < 8; ++j) o[j] = f2bf1((float)q[j] * s);
        *(bf16x8*)(bpk + (size_t)idx * 8) = o;
    }
}

// ---------------------------------------------------------------------------
// Fused: block = 32 token rows, 512 threads (8 waves), grid T/32 = 512.
// Phase 1: double-buffered LDS staging of x (dense coalesced loads),
//          8-wave split-K MFMA, ONE barrier per chunk, 2-chunk prefetch.
// Phase 2: two-round fp32 cross-wave reduce -> h bf16 in LDS.
// Phase 3: out = h @ b^T from packed bpk, 32x32x16 MFMA, coalesced stores.
// ---------------------------------------------------------------------------
__global__ __launch_bounds__(512, 4) void fused_kernel(
        const float* __restrict__ x, const short* __restrict__ apk,
        const short* __restrict__ bpk, float* __restrict__ out) {
    // smem: stage double buffer 2 x (32 rows x 512 bf16) = 65536 B,
    //       overlaid by red[4][32][68] f32 (34816 B) in phase 2;
    //       h_lds 32x80 bf16 = 5120 B after the stage region.
    __shared__ __align__(16) char smem[65536 + 5120];
    float* red   = (float*)smem;
    short* h_lds = (short*)(smem + 65536);

    const int tid  = threadIdx.x;
    const int lane = tid & 63;
    const int wave = tid >> 6;
    const int rb   = blockIdx.x * M_BLK;

    const int srow = tid >> 7;               // 0..3
    const int scol = (tid & 127) << 2;       // float col 0,4,...,508
    const float* xb = x + (size_t)rb * D_MODEL;

    // ---- prologue: stage chunk 0, prefetch chunk 1 ----
    f32x4 xr[8];
    #pragma unroll
    for (int r = 0; r < 8; ++r)
        xr[r] = *(const f32x4*)(xb + (size_t)(r * 4 + srow) * D_MODEL + scol);
    #pragma unroll
    for (int r = 0; r < 8; ++r) {
        const int row = r * 4 + srow;
        int byte = row * 1024 + (scol << 1);
        byte ^= (row & 7) << 4;
        union { uint32_t w[2]; uint2 u; } p;
        p.w[0] = pkbf(xr[r][0], xr[r][1]);
        p.w[1] = pkbf(xr[r][2], xr[r][3]);
        *(uint2*)(smem + byte) = p.u;
    }
    #pragma unroll
    for (int r = 0; r < 8; ++r)
        xr[r] = *(const f32x4*)(xb + (size_t)(r * 4 + srow) * D_MODEL + KC + scol);
    __syncthreads();

    f32x4 acc[2][4];
    #pragma unroll
    for (int m = 0; m < 2; ++m)
        #pragma unroll
        for (int n = 0; n < 4; ++n)
            acc[m][n] = (f32x4){0.f, 0.f, 0.f, 0.f};

    // ---- main K loop: one barrier per chunk ----
    for (int c = 0; c < NCH; ++c) {
        const char* sb = smem + (c & 1) * 32768;
        #pragma unroll
        for (int ks = 0; ks < 2; ++ks) {
            const int kin = wave * 64 + ks * 32 + ((lane >> 4) << 3);
            bf16x8 af[2];
            #pragma unroll
            for (int m = 0; m < 2; ++m) {
                const int row = m * 16 + (lane & 15);
                int byte = row * 1024 + (kin << 1);
                byte ^= (row & 7) << 4;
                af[m] = *(const bf16x8*)(sb + byte);
            }
            const int kbg = c * 16 + wave * 2 + ks;      // global 32-k block
            #pragma unroll
            for (int n = 0; n < 4; ++n) {
                bf16x8 bf = *(const bf16x8*)(apk + ((size_t)((kbg * 4 + n) * 64 + lane) << 3));
                #pragma unroll
                for (int m = 0; m < 2; ++m)
                    acc[m][n] = __builtin_amdgcn_mfma_f32_16x16x32_bf16(
                        af[m], bf, acc[m][n], 0, 0, 0);
            }
        }
        if (c < NCH - 1) {
            char* sw = smem + ((c + 1) & 1) * 32768;
            #pragma unroll
            for (int r = 0; r < 8; ++r) {
                const int row = r * 4 + srow;
                int byte = row * 1024 + (scol << 1);
                byte ^= (row & 7) << 4;
                union { uint32_t w[2]; uint2 u; } p;
                p.w[0] = pkbf(xr[r][0], xr[r][1]);
                p.w[1] = pkbf(xr[r][2], xr[r][3]);
                *(uint2*)(sw + byte) = p.u;
            }
            if (c < NCH - 2) {
                #pragma unroll
                for (int r = 0; r < 8; ++r)
                    xr[r] = *(const f32x4*)(xb + (size_t)(r * 4 + srow) * D_MODEL
                                            + (size_t)(c + 2) * KC + scol);
            }
        }
        __syncthreads();
    }

    // ---- phase 2: cross-wave reduction (red overlays stage) ----
    const int r4 = (lane >> 4) << 2;
    if (wave < 4) {
        #pragma unroll
        for (int m = 0; m < 2; ++m)
            #pragma unroll
            for (int n = 0; n < 4; ++n)
                #pragma unroll
                for (int j = 0; j < 4; ++j)
                    red[(wave * 32 + m * 16 + r4 + j) * 68 + n * 16 + (lane & 15)] =
                        acc[m][n][j];
    }
    __syncthreads();
    if (wave >= 4) {
        #pragma unroll
        for (int m = 0; m < 2; ++m)
            #pragma unroll
            for (int n = 0; n < 4; ++n)
                #pragma unroll
                for (int j = 0; j < 4; ++j)
                    red[((wave - 4) * 32 + m * 16 + r4 + j) * 68 + n * 16 + (lane & 15)] +=
                        acc[m][n][j];
    }
    __syncthreads();
    for (int e = tid; e < 32 * 64; e += 512) {
        const int r = e >> 6, cc = e & 63;
        float s = red[(0 * 32 + r) * 68 + cc] + red[(1 * 32 + r) * 68 + cc]
                + red[(2 * 32 + r) * 68 + cc] + red[(3 * 32 + r) * 68 + cc];
        h_lds[r * 80 + cc] = f2bf1(s);
    }
    __syncthreads();

    // ---- phase 3: out[32][4096] = h @ b^T; wave w -> cols [w*512, +512) ----
    bf16x8 hf[4];
    #pragma unroll
    for (int ks = 0; ks < 4; ++ks)
        hf[ks] = *(const bf16x8*)(h_lds + (lane & 31) * 80 + ks * 16 + ((lane >> 5) << 3));

    #pragma unroll
    for (int n = 0; n < 16; ++n) {
        const int cb32 = wave * 16 + n;
        const int col  = cb32 * 32 + (lane & 31);
        f32x16 a2;
        #pragma unroll
        for (int j = 0; j < 16; ++j) a2[j] = 0.f;
        #pragma unroll
        for (int ks = 0; ks < 4; ++ks) {
            bf16x8 bf = *(const bf16x8*)(bpk + ((size_t)((cb32 * 4 + ks) * 64 + lane) << 3));
            a2 = __builtin_amdgcn_mfma_f32_32x32x16_bf16(hf[ks], bf, a2, 0, 0, 0);
        }
        #pragma unroll
        for (int reg = 0; reg < 16; ++reg) {
            const int r = (reg & 3) + 8 * (reg >> 2) + ((lane >> 5) << 2);
            out[(size_t)(rb + r) * D_MODEL + col] = a2[reg];
        }
    }
}

// ---------------------------------------------------------------------------
extern "C" void kernel_launch(void* const* d_in, const int* in_sizes, int n_in,
                              void* d_out, int out_size, void* d_ws, size_t ws_size,
                              hipStream_t stream) {
    (void)n_in; (void)out_size; (void)ws_size;
    const float* x   = (const float*)d_in[0];
    const int*   qa  = (const int*)d_in[1];
    const float* qas = (const float*)d_in[2];
    const int*   qb  = (const int*)d_in[3];
    const float* qbs = (const float*)d_in[4];
    float* out = (float*)d_out;

    const int T = in_sizes[0] / D_MODEL;   // 16384

    short* apk = (short*)d_ws;                       // 64*4096 bf16 packed
    short* bpk = apk + (size_t)RANK * D_MODEL;       // 4096*64 bf16 packed

    dequant_pack_kernel<<<128, 256, 0, stream>>>(qa, qas, qb, qbs, apk, bpk);
    fused_kernel<<<T / M_BLK, 512, 0, stream>>>(x, apk, bpk, out);
}